// Round 5
// baseline (105.737 us; speedup 1.0000x reference)
//
#include <hip/hip_runtime.h>

// HBV hydrological model, MI355X (gfx950).
// x (365,1000,3) f32, parameters (365,1000,14,16) f32, staind i32 -> out (365,1000,1) f32.
//
// Latency-bound serial scan: 16000 independent (g,mu) chains, grid gives ~1 wave/CU,
// so per-wave in-order stalls are wall time. R5: 2 chains per lane (mu=ml, ml+8 of the
// SAME g) to fill dependency gaps with independent work; shared P/T/E loads; one
// param pointer with immediate offsets; 3-DPP 8-lane reduce; depth-5 ring (exact fit).
// R4 carried: per-step Q -> LDS (lgkmcnt), single coalesced flush (keeps vmcnt clean).

static constexpr int   NSTEP = 365;
static constexpr int   NGRID = 1000;
static constexpr int   MU    = 16;
static constexpr float PRECS = 1e-5f;
static constexpr int   DEPTH = 5;      // ring depth; 365 = 5 prologue + 72*5 main + 5 epi

__device__ __forceinline__ float fast_pow(float xx, float yy) {
    // arg > 0 guaranteed (SM >= PRECS); caller clamps result
    return __builtin_amdgcn_exp2f(yy * __builtin_amdgcn_logf(xx));
}

// DPP cross-lane add: pure VALU, no LDS pipe.
template <int CTRL>
__device__ __forceinline__ float dpp_add(float v) {
    int r = __builtin_amdgcn_update_dpp(0, __float_as_int(v), CTRL, 0xF, 0xF, true);
    return v + __int_as_float(r);
}

__global__ __launch_bounds__(64)
void hbv_kernel(const float* __restrict__ x,
                const float* __restrict__ par,
                const int*   __restrict__ staind_p,
                float*       __restrict__ out)
{
    __shared__ float qlds[NSTEP * 8];      // 11680 B: per-step Q-mean, 8 g per block

    const int lane = threadIdx.x;          // 0..63
    const int ml   = lane & 7;             // chain A: mu=ml, chain B: mu=ml+8
    const int gl   = lane >> 3;            // 0..7 local grid index
    const int g    = blockIdx.x * 8 + gl;
    const int staind = *staind_p;

    const size_t tstride = (size_t)NGRID * 14 * MU;   // params per timestep
    const int    xstride = NGRID * 3;

    // ---- static params for both chains: parameters[staind, g, i, ml + 8c] ----
    float FC[2], K0[2], K1[2], K2[2], PERCp[2], UZL[2], TT[2], CFMAX[2],
          CRF[2], CWH[2], C[2], rFC[2], rLPFC[2];
    {
        const float* psb = par + (size_t)staind * tstride + (size_t)g * 14 * MU + ml;
#pragma unroll
        for (int c = 0; c < 2; ++c) {
            const float* ps = psb + 8 * c;
            FC[c]    = 50.0f  + ps[ 1*MU] * (1000.0f - 50.0f);
            K0[c]    = 0.05f  + ps[ 2*MU] * (0.9f  - 0.05f);
            K1[c]    = 0.01f  + ps[ 3*MU] * (0.5f  - 0.01f);
            K2[c]    = 0.001f + ps[ 4*MU] * (0.2f  - 0.001f);
            const float LP = 0.2f + ps[ 5*MU] * (1.0f - 0.2f);
            PERCp[c] =          ps[ 6*MU] * 10.0f;
            UZL[c]   =          ps[ 7*MU] * 100.0f;
            TT[c]    = -2.5f  + ps[ 8*MU] * 5.0f;
            CFMAX[c] = 0.5f   + ps[ 9*MU] * (10.0f - 0.5f);
            CRF[c]   =          ps[10*MU] * 0.1f * CFMAX[c];
            CWH[c]   =          ps[11*MU] * 0.2f;
            C[c]     =          ps[13*MU] * 1.0f;
            rFC[c]   = 1.0f / FC[c];
            rLPFC[c] = 1.0f / (LP * FC[c]);
        }
    }

    // ---- state (2 chains) ----
    float SP[2]  = {1e-3f, 1e-3f}, MW[2]  = {1e-3f, 1e-3f}, SM[2] = {1e-3f, 1e-3f},
          SUZ[2] = {1e-3f, 1e-3f}, SLZ[2] = {1e-3f, 1e-3f};

    // ---- one chain step (c is a literal at every call site -> static indexing) ----
    auto chain = [&](int c, float P, float T, float E, float p0, float p12) -> float {
        const float BETA   = 1.0f + p0  * 5.0f;
        const float BETAET = 0.3f + p12 * 4.7f;
        const float RAIN = (T >= TT[c]) ? P : 0.0f;
        const float SNOW = P - RAIN;                        // exact split
        const float dT   = T - TT[c];
        const float acap = fmaxf(CFMAX[c] * dT, 0.0f);      // off-chain
        const float bcap = fmaxf(CRF[c] * (-dT), 0.0f);     // off-chain

        const float SP1  = SP[c] + SNOW;
        const float melt = fminf(acap, SP1);
        const float SP2  = SP1 - melt;
        const float MW1  = MW[c] + melt;
        const float refr = fminf(bcap, MW1);
        const float MW2  = MW1 - refr;
        const float SP3  = SP2 + refr;
        const float lim  = CWH[c] * SP3;
        const float tosoil = fmaxf(MW2 - lim, 0.0f);
        SP[c] = SP3;
        MW[c] = fminf(MW2, lim);                            // MW2 - tosoil (exact)

        const float wet    = fminf(fast_pow(SM[c] * rFC[c], BETA), 1.0f);
        const float excess = fmaxf(SM[c] - FC[c], 0.0f);
        const float SM1    = fminf(SM[c], FC[c]);           // SM - excess (exact)
        const float evapf  = fminf(fast_pow(SM1 * rLPFC[c], BETAET), 1.0f);
        const float SM2    = fmaxf(SM1 - E * evapf, PRECS); // ETact fold (exact)
        const float rt     = RAIN + tosoil;
        const float recharge = rt * wet;
        const float SM3    = SM2 + rt - recharge;
        const float CSLZ   = C[c] * SLZ[c];
        const float cap    = fminf(SLZ[c], CSLZ * (1.0f - fminf(SM3 * rFC[c], 1.0f)));
        SM[c] = fmaxf(SM3 + cap, PRECS);
        const float SLZ1   = fmaxf(SLZ[c] - cap, PRECS);

        const float SUZ1 = SUZ[c] + recharge + excess;
        const float PERC = fminf(SUZ1, PERCp[c]);
        const float SUZ2 = SUZ1 - PERC;
        const float w0   = fmaxf(SUZ2 - UZL[c], 0.0f);
        const float Q0   = K0[c] * w0;
        const float SUZ3 = SUZ2 - Q0;
        const float Q1   = K1[c] * SUZ3;
        SUZ[c] = SUZ3 - Q1;
        const float SLZ2 = SLZ1 + PERC;
        const float Q2   = K2[c] * SLZ2;
        SLZ[c] = SLZ2 - Q2;
        return Q0 + Q1 + Q2;
    };

    auto stepf = [&](int t, float P, float T, float E,
                     float p0a, float p12a, float p0b, float p12b) {
        float Q = chain(0, P, T, E, p0a, p12a) + chain(1, P, T, E, p0b, p12b);
        // sum over the 8-lane group (x2 chains = all 16 mu): xor1, xor2, half-mirror
        Q = dpp_add<0xB1>(Q);    // quad_perm [1,0,3,2] : xor 1
        Q = dpp_add<0x4E>(Q);    // quad_perm [2,3,0,1] : xor 2
        Q = dpp_add<0x141>(Q);   // row_half_mirror     : across quads in 8
        qlds[t * 8 + gl] = Q * 0.0625f;   // same addr+value across the 8 lanes
    };

    // ---- prefetch ring (depth 5; single param pointer, imm offsets 0/32B/768B/800B) ----
    const float* pdp = par + (size_t)g * 14 * MU + ml;
    const float* xpp = x   + (size_t)g * 3;

    float bP[DEPTH], bT[DEPTH], bE[DEPTH], b0[2][DEPTH], b12[2][DEPTH];
#pragma unroll
    for (int j = 0; j < DEPTH; ++j) {      // rows 0..4; pointers end at row 5
        b0[0][j]  = pdp[0];
        b12[0][j] = pdp[12*MU];
        b0[1][j]  = pdp[8];
        b12[1][j] = pdp[12*MU + 8];
        bP[j] = xpp[0]; bT[j] = xpp[1]; bE[j] = xpp[2];
        pdp += tstride;
        xpp += xstride;
    }

    // main: steps 0..359, prefetch rows 5..364 -- unconditional, exact fit
    for (int tb = 0; tb < 360; tb += DEPTH) {
#pragma unroll
        for (int j = 0; j < DEPTH; ++j) {
            const float P = bP[j], T = bT[j], E = bE[j];
            const float p0a = b0[0][j], p12a = b12[0][j];
            const float p0b = b0[1][j], p12b = b12[1][j];
            b0[0][j]  = pdp[0];
            b12[0][j] = pdp[12*MU];
            b0[1][j]  = pdp[8];
            b12[1][j] = pdp[12*MU + 8];
            bP[j] = xpp[0]; bT[j] = xpp[1]; bE[j] = xpp[2];
            pdp += tstride;
            xpp += xstride;
            stepf(tb + j, P, T, E, p0a, p12a, p0b, p12b);
        }
    }

    // epilogue: steps 360..364 from ring slots, no prefetch
#pragma unroll
    for (int j = 0; j < DEPTH; ++j)
        stepf(360 + j, bP[j], bT[j], bE[j],
              b0[0][j], b12[0][j], b0[1][j], b12[1][j]);

    // ---- flush: LDS -> global, coalesced (1 wave/block: no barrier needed) ----
    const int gbase = blockIdx.x * 8;
    for (int i = lane; i < NSTEP * 8; i += 64) {
        out[(i >> 3) * NGRID + gbase + (i & 7)] = qlds[i];
    }
}

extern "C" void kernel_launch(void* const* d_in, const int* in_sizes, int n_in,
                              void* d_out, int out_size, void* d_ws, size_t ws_size,
                              hipStream_t stream) {
    const float* x      = (const float*)d_in[0];
    const float* par    = (const float*)d_in[1];
    const int*   staind = (const int*)d_in[2];
    float*       out    = (float*)d_out;

    hipLaunchKernelGGL(hbv_kernel, dim3(NGRID / 8), dim3(64), 0, stream,
                       x, par, staind, out);
}

// Round 6
// 69.073 us; speedup vs baseline: 1.5308x; 1.5308x over previous
//
#include <hip/hip_runtime.h>

// HBV hydrological model, MI355X (gfx950).
// x (365,1000,3) f32, parameters (365,1000,14,16) f32, staind i32 -> out (365,1000,1) f32.
//
// Latency-bound serial scan: 250 waves, 1 wave/CU; per-wave in-order stalls are wall
// time. R5 lesson: never condense waves for ILP at <=1 wave/CU (2 chains/lane = 1.6x
// regression). R6: back to 1 chain/lane + manual 2-stage software pipeline
// (soilB(t) || snowA(t+1), independent chains adjacent in one basic block) + uniform
// SGPR base advance (addressing off the VALU pipe).
// Carried: depth-10 ring, DPP 16-lane reduce, LDS-staged output (vmcnt stays clean).

static constexpr int   NSTEP = 365;
static constexpr int   NGRID = 1000;
static constexpr int   MU    = 16;
static constexpr float PRECS = 1e-5f;
static constexpr int   DEPTH = 10;

__device__ __forceinline__ float fast_pow(float xx, float yy) {
    // arg > 0 guaranteed (SM >= PRECS); caller clamps result
    return __builtin_amdgcn_exp2f(yy * __builtin_amdgcn_logf(xx));
}

// DPP cross-lane add: pure VALU, no LDS pipe.
template <int CTRL>
__device__ __forceinline__ float dpp_add(float v) {
    int r = __builtin_amdgcn_update_dpp(0, __float_as_int(v), CTRL, 0xF, 0xF, true);
    return v + __int_as_float(r);
}

__global__ __launch_bounds__(64)
void hbv_kernel(const float* __restrict__ x,
                const float* __restrict__ par,
                const int*   __restrict__ staind_p,
                float*       __restrict__ out)
{
    __shared__ float qlds[NSTEP * 4];      // 5840 B: per-step Q-mean for 4 g

    const int lane = threadIdx.x;          // 0..63
    const int m    = lane & 15;            // mu index
    const int gl   = lane >> 4;            // 0..3 local g
    const int g    = blockIdx.x * 4 + gl;
    const int staind = *staind_p;

    const size_t tstride = (size_t)NGRID * 14 * MU;   // 224000 elems / timestep
    const int    xstride = NGRID * 3;

    // per-lane constant element offsets (VGPR); step base advances uniformly (SGPR)
    const int lp = g * (14 * MU) + m;
    const int lx = g * 3;

    // ---- static params: parameters[staind, g, i, m] ----
    const float* ps = par + (size_t)staind * tstride + lp;
    const float FC    = 50.0f  + ps[ 1*MU] * (1000.0f - 50.0f);
    const float K0    = 0.05f  + ps[ 2*MU] * (0.9f  - 0.05f);
    const float K1    = 0.01f  + ps[ 3*MU] * (0.5f  - 0.01f);
    const float K2    = 0.001f + ps[ 4*MU] * (0.2f  - 0.001f);
    const float LP    = 0.2f   + ps[ 5*MU] * (1.0f  - 0.2f);
    const float PERCp =          ps[ 6*MU] * 10.0f;
    const float UZL   =          ps[ 7*MU] * 100.0f;
    const float TT    = -2.5f  + ps[ 8*MU] * 5.0f;
    const float CFMAX = 0.5f   + ps[ 9*MU] * (10.0f - 0.5f);
    const float CRF   =          ps[10*MU] * 0.1f * CFMAX;
    const float CWH   =          ps[11*MU] * 0.2f;
    const float C     =          ps[13*MU] * 1.0f;
    const float rFC   = 1.0f / FC;
    const float rLPFC = 1.0f / (LP * FC);

    // ---- state ----
    float SP = 1e-3f, MW = 1e-3f, SM = 1e-3f, SUZ = 1e-3f, SLZ = 1e-3f;
    float rt_pipe = 0.0f;                  // RAIN + tosoil, handed from A(t) to B(t)

    // ---- stage A: snow module for step t (SP, MW) -> rt_pipe ----
    auto snowA = [&](float P, float T) {
        const float RAIN = (T >= TT) ? P : 0.0f;
        const float SNOW = P - RAIN;                      // exact split
        const float dT   = T - TT;
        const float acap = fmaxf(CFMAX * dT, 0.0f);
        const float bcap = fmaxf(CRF * (TT - T), 0.0f);
        const float SP1  = SP + SNOW;
        const float melt = fminf(acap, SP1);
        const float SP2  = SP1 - melt;
        const float MW1  = MW + melt;
        const float refr = fminf(bcap, MW1);
        const float MW2  = MW1 - refr;
        const float SP3  = SP2 + refr;
        const float lim  = CWH * SP3;
        const float tosoil = fmaxf(MW2 - lim, 0.0f);
        SP = SP3;
        MW = fminf(MW2, lim);                             // MW2 - tosoil (exact)
        rt_pipe = RAIN + tosoil;
    };

    // ---- stage B: soil + response for step t (SM, SUZ, SLZ) -> Q -> LDS ----
    auto soilB = [&](int t, float E, float p0, float p12) {
        const float rt     = rt_pipe;
        const float BETA   = 1.0f + p0  * 5.0f;
        const float BETAET = 0.3f + p12 * 4.7f;
        const float wet    = fminf(fast_pow(SM * rFC, BETA), 1.0f);
        const float excess = fmaxf(SM - FC, 0.0f);
        const float SM1    = fminf(SM, FC);               // SM - excess (exact)
        const float evapf  = fminf(fast_pow(SM1 * rLPFC, BETAET), 1.0f);
        const float SM2    = fmaxf(SM1 - E * evapf, PRECS); // ETact fold (exact)
        const float recharge = rt * wet;
        const float SM3    = SM2 + rt - recharge;
        const float cap    = fminf(SLZ, C * SLZ * (1.0f - fminf(SM3 * rFC, 1.0f)));
        SM = fmaxf(SM3 + cap, PRECS);
        const float SLZ1   = fmaxf(SLZ - cap, PRECS);

        const float SUZ1 = SUZ + recharge + excess;
        const float PERC = fminf(SUZ1, PERCp);
        const float SUZ2 = SUZ1 - PERC;
        const float Q0   = K0 * fmaxf(SUZ2 - UZL, 0.0f);
        const float SUZ3 = SUZ2 - Q0;
        const float Q1   = K1 * SUZ3;
        SUZ = SUZ3 - Q1;
        const float SLZ2 = SLZ1 + PERC;
        const float Q2   = K2 * SLZ2;
        SLZ = SLZ2 - Q2;

        float Q = Q0 + Q1 + Q2;
        Q = dpp_add<0xB1>(Q);    // xor 1
        Q = dpp_add<0x4E>(Q);    // xor 2
        Q = dpp_add<0x141>(Q);   // row_half_mirror
        Q = dpp_add<0x140>(Q);   // row_mirror -> 16-lane sum
        qlds[t * 4 + gl] = Q * 0.0625f;   // same addr+value across 16 lanes
    };

    // ---- depth-10 ring; uniform step-base pointers (SGPR), lane offset in VGPR ----
    const float* parv = par;   // + t*tstride, uniform advance
    const float* xv   = x;     // + t*xstride, uniform advance

    float bP[DEPTH], bT[DEPTH], bE[DEPTH], b0[DEPTH], b12[DEPTH];
#pragma unroll
    for (int j = 0; j < DEPTH; ++j) {      // slots 0..9 = steps 0..9
        b0[j]  = parv[lp];
        b12[j] = parv[lp + 12*MU];
        bP[j]  = xv[lx + 0];
        bT[j]  = xv[lx + 1];
        bE[j]  = xv[lx + 2];
        parv += tstride;
        xv   += xstride;
    }

    snowA(bP[0], bT[0]);                   // A(0) -> rt_pipe

    // main: B(0..349), A(1..350), refills steps 10..359
    for (int tb = 0; tb < 350; tb += DEPTH) {
#pragma unroll
        for (int j = 0; j < DEPTH; ++j) {
            const int t = tb + j;
            const float E = bE[j], p0 = b0[j], p12 = b12[j];
            // refill slot j <- step t+10
            b0[j]  = parv[lp];
            b12[j] = parv[lp + 12*MU];
            bP[j]  = xv[lx + 0];
            bT[j]  = xv[lx + 1];
            bE[j]  = xv[lx + 2];
            parv += tstride;
            xv   += xstride;
            // two independent chains, adjacent for the scheduler:
            soilB(t, E, p0, p12);                            // uses rt_pipe = rt(t)
            snowA(bP[(j + 1) % DEPTH], bT[(j + 1) % DEPTH]); // -> rt(t+1)
        }
    }

    // peeled sweep: B(350..359), A(351..360); refill slots 0..4 <- steps 360..364
#pragma unroll
    for (int j = 0; j < DEPTH; ++j) {
        const int t = 350 + j;
        const float E = bE[j], p0 = b0[j], p12 = b12[j];
        if (j < 5) {
            b0[j]  = parv[lp];
            b12[j] = parv[lp + 12*MU];
            bP[j]  = xv[lx + 0];
            bT[j]  = xv[lx + 1];
            bE[j]  = xv[lx + 2];
            parv += tstride;
            xv   += xstride;
        }
        soilB(t, E, p0, p12);
        snowA(bP[(j + 1) % DEPTH], bT[(j + 1) % DEPTH]);
    }

    // epilogue: B(360..364) from slots 0..4, A(361..364) from slots 1..4
#pragma unroll
    for (int j = 0; j < 5; ++j) {
        soilB(360 + j, bE[j], b0[j], b12[j]);
        if (j < 4) snowA(bP[j + 1], bT[j + 1]);
    }

    // ---- flush: LDS -> global, coalesced (1 wave/block: no barrier needed) ----
    const int gbase = blockIdx.x * 4;
    for (int i = lane; i < NSTEP * 4; i += 64) {
        out[(i >> 2) * NGRID + gbase + (i & 3)] = qlds[i];
    }
}

extern "C" void kernel_launch(void* const* d_in, const int* in_sizes, int n_in,
                              void* d_out, int out_size, void* d_ws, size_t ws_size,
                              hipStream_t stream) {
    const float* x      = (const float*)d_in[0];
    const float* par    = (const float*)d_in[1];
    const int*   staind = (const int*)d_in[2];
    float*       out    = (float*)d_out;

    hipLaunchKernelGGL(hbv_kernel, dim3(NGRID / 4), dim3(64), 0, stream,
                       x, par, staind, out);
}